// Round 6
// baseline (243.235 us; speedup 1.0000x reference)
//
#include <hip/hip_runtime.h>

// MHA forward, B=2, S=2048, D=1024, H=16, Dk=64, causal, RoPE. fp32 I/O.
// Internal bf16 MFMA 16x16x32, fp32 accum.
// R11: RoPE table. R12/R13 un-paired attn: FALSIFIED (spills / dispatch
// imbalance). R14 phase-fused dual proc: NEUTRAL. R15 in-register P via
// swapped QK + cvt_pk + bpermute: NEUTRAL (72us invariant across 3
// structures) -> limiter is 2 waves/SIMD exposing every latency.
// R17: 512-thread attn blocks. Waves 0-3 target tile qtA, waves 4-7 tile
// qtB; one proc/wave/iter (half chain), 4 waves/SIMD (2 blocks/CU).
// Balanced 17-iter schedule: grpA does KV tiles 0..16 (target A while
// i<=qtA, then target B); grpB does tiles 0..qtA, then 17..qtB, idle at
// most 1 iter. Equal-work blocks preserved. Tile A finalized+written at
// the switch (frees o/qf regs); tile-B partials merged via LDS (aliases
// Vt). K loads issued before the staging barriers (L2 latency hidden);
// no K-prefetch regs -> VGPR<=128 under __launch_bounds__(512,4).

typedef unsigned short u16;
typedef __attribute__((ext_vector_type(8))) short short8;   // 8 bf16 = 4 VGPRs
typedef __attribute__((ext_vector_type(4))) float float4v;  // MFMA C/D

typedef const __attribute__((address_space(1))) void GV;    // global
typedef __attribute__((address_space(3))) void LV;          // LDS

#define VSTR 72   // attn Vt row stride (u16): 144B rows, 2-way read banks
#define QSCL 0.18033688011112042f   // 0.125 * log2(e)

__device__ __forceinline__ u16 f2b(float f) {
    union { float f; unsigned int i; } t; t.f = f;
    unsigned int r = t.i + 0x7fffu + ((t.i >> 16) & 1u);   // RNE
    return (u16)(r >> 16);
}

// ---------------- fused fp32 -> bf16 converter ------------------------------
__global__ __launch_bounds__(256) void cvt_all(
    const float4* __restrict__ x,  const float4* __restrict__ wq,
    const float4* __restrict__ wk, const float4* __restrict__ wv,
    const float4* __restrict__ wo,
    u16* __restrict__ xb, u16* __restrict__ wcat, u16* __restrict__ wob)
{
    const int i = blockIdx.x * 256 + threadIdx.x;
    const float4* s; u16* d; int off;
    if (i < 524288) { s = x; d = xb; off = i; }
    else {
        const int widx = i - 524288;
        const int w = widx >> 17, o = widx & 131071;
        switch (w) {
            case 0:  s = wq; d = wcat;              break;
            case 1:  s = wk; d = wcat + (1 << 20);  break;
            case 2:  s = wv; d = wcat + (2 << 20);  break;
            default: s = wo; d = wob;               break;
        }
        off = o;
    }
    float4 a = s[2 * off], b = s[2 * off + 1];
    u16 t[8] = {f2b(a.x), f2b(a.y), f2b(a.z), f2b(a.w),
                f2b(b.x), f2b(b.y), f2b(b.z), f2b(b.w)};
    reinterpret_cast<int4*>(d)[off] = *reinterpret_cast<int4*>(t);
}

// ---------------- RoPE cos/sin table: tab[pos*32+fi] = {cos, sin} ----------
__global__ __launch_bounds__(256) void rope_tab(float2* __restrict__ tab) {
    const int i = blockIdx.x * 256 + threadIdx.x;   // 0..65535
    const int pos = i >> 5, fi = i & 31;
    const float freq = exp2f((float)fi * -0.4152410118609203f);  // -log2(1e4)/32
    float sn, cs; sincosf((float)pos * freq, &sn, &cs);
    tab[i] = make_float2(cs, sn);
}

// ---------------------------------------------------------------------------
// Y[m][n] = sum_k X[m][k] * W[n][k]; 128(m) x NT*32(n) x 64(k) tiles.
// Staging: global_load_lds width=16. LDS: 64-elem rows, 16B unit u stored at
// phys u^(row&7) (lane-contiguous DMA dest, swizzled ds_read_b128).
// ROPE=1: route cols to Yq/Yk/Yv, RoPE q,k via table, scale q by QSCL.
// XCD swizzle: block g -> xcd=g&7 owns m-strips [xcd*4, xcd*4+4).
// ---------------------------------------------------------------------------
template<int NT, int ROPE, int NBLK>
__global__ __launch_bounds__(256) void gemm_tile(
    const u16* __restrict__ X, const u16* __restrict__ Wb,
    u16* __restrict__ Yq, u16* __restrict__ Yk, u16* __restrict__ Yv,
    float* __restrict__ Yf, const float2* __restrict__ tab)
{
    __shared__ u16 As[128 * 64];
    __shared__ u16 Bs[NT * 32 * 64];

    const int tid  = threadIdx.x;
    const int wave = tid >> 6;
    const int lane = tid & 63;
    const int quad = lane >> 4;
    const int l16  = lane & 15;
    const int wm = (wave >> 1) * 64, wn = (wave & 1) * (NT * 16);
    const int g = blockIdx.x;
    const int rr = g >> 3;
    const int m0 = ((g & 7) * 4 + rr / NBLK) * 128;
    const int n0 = (rr % NBLK) * (NT * 32);
    const int lrow = lane >> 3;                         // 0..7 within 8-row slab
    const int cg8  = (lane & 7) ^ lrow;                 // swizzled global unit

    float4v acc[4][NT];
#pragma unroll
    for (int mt = 0; mt < 4; mt++)
#pragma unroll
        for (int nt = 0; nt < NT; nt++) acc[mt][nt] = (float4v){0.f, 0.f, 0.f, 0.f};

    for (int kb = 0; kb < 1024; kb += 64) {
        __syncthreads();                                 // prev reads done
#pragma unroll
        for (int t = 0; t < 4; t++) {                    // stage A: 4x 1KB/wave
            const int I = wave * 4 + t;
            const u16* gp = X + (size_t)(m0 + I * 8 + lrow) * 1024 + kb + cg8 * 8;
            __builtin_amdgcn_global_load_lds((GV*)gp, (LV*)&As[I * 512], 16, 0, 0);
        }
#pragma unroll
        for (int t = 0; t < NT; t++) {                   // stage B: NTx 1KB/wave
            const int I = wave * NT + t;
            const u16* gp = Wb + (size_t)(n0 + I * 8 + lrow) * 1024 + kb + cg8 * 8;
            __builtin_amdgcn_global_load_lds((GV*)gp, (LV*)&Bs[I * 512], 16, 0, 0);
        }
        __syncthreads();                                 // vmcnt drained here
#pragma unroll
        for (int ks = 0; ks < 2; ks++) {
            const int su = ((ks * 4 + quad) ^ (l16 & 7)) * 8;   // swizzled unit
            short8 af[4], bf[NT];
#pragma unroll
            for (int t = 0; t < 4; t++)
                af[t] = *reinterpret_cast<const short8*>(&As[(wm + t * 16 + l16) * 64 + su]);
#pragma unroll
            for (int t = 0; t < NT; t++)
                bf[t] = *reinterpret_cast<const short8*>(&Bs[(wn + t * 16 + l16) * 64 + su]);
#pragma unroll
            for (int mt = 0; mt < 4; mt++)
#pragma unroll
                for (int nt = 0; nt < NT; nt++)
                    acc[mt][nt] = __builtin_amdgcn_mfma_f32_16x16x32_bf16(af[mt], bf[nt], acc[mt][nt], 0, 0, 0);
        }
    }

    if (ROPE) {
#pragma unroll
        for (int nt = 0; nt < NT; nt++) {
            const int cg = n0 + wn + nt * 16 + l16;      // global col 0..3071
            const int buf = cg >> 10;                    // 0=q 1=k 2=v
            const int c = cg & 1023;
            u16* dst = (buf == 0) ? Yq : ((buf == 1) ? Yk : Yv);
            const bool rp = (buf < 2);
            const float scl = (buf == 0) ? QSCL : 1.0f;
            const int fi = (cg & 63) >> 1;               // pair index in head
#pragma unroll
            for (int mt = 0; mt < 4; mt++)
#pragma unroll
                for (int r = 0; r < 4; r++) {
                    const int row = m0 + wm + mt * 16 + quad * 4 + r;
                    float v = acc[mt][nt][r];
                    if (rp) {
                        const float2 t = tab[((row & 2047) << 5) + fi];
                        const float partner = __shfl_xor(v, 1);
                        v = (l16 & 1) ? fmaf(v, t.x,  partner * t.y)
                                      : fmaf(v, t.x, -partner * t.y);
                    }
                    dst[(size_t)row * 1024 + c] = f2b(v * scl);
                }
        }
    } else {
#pragma unroll
        for (int nt = 0; nt < NT; nt++) {
            const int col = n0 + wn + nt * 16 + l16;
#pragma unroll
            for (int mt = 0; mt < 4; mt++)
#pragma unroll
                for (int r = 0; r < 4; r++) {
                    const int row = m0 + wm + mt * 16 + quad * 4 + r;
                    Yf[(size_t)row * 1024 + col] = acc[mt][nt][r];
                }
        }
    }
}

// ---------------------------------------------------------------------------
// Flash causal attention, 512 threads (8 waves), 512 equal-work blocks.
// Waves 0-3 (grp A): q-tile qtA; waves 4-7 (grp B): q-tile qtB=31-qtA.
// Balanced schedule (17 iters): grpA KV tiles 0..16 (target A for i<=qtA,
// then target B); grpB KV tiles 0..qtA then 17..qtB (idle <=1 iter).
// Swapped QK^T (R15): P in-register, cvt_pk + bpermute redistribution.
// Unnormalized softmax (q pre-scaled 0.125*log2e, p=exp2f). Two Vt LDS
// buffers; K loaded per-iter before the staging barriers. Tile A written
// at the switch; tile B merged (A-partial + B-partial) via LDS. O aliases
// Q (each block owns its two tiles' rows exclusively).
// ---------------------------------------------------------------------------
__global__ __launch_bounds__(512, 4) void attn_kernel(
    const u16* Q, const u16* __restrict__ K,
    const u16* __restrict__ V, u16* O)
{
    __shared__ union {
        u16 vt[2][64 * VSTR];                         // 2 x 9216 B
        struct { float o[4][64][17]; float s[4][64]; } m;  // 18432 B
    } sm;

    const int tid  = threadIdx.x;
    const int wave = tid >> 6;          // 0..7
    const int grp  = wave >> 2;         // 0 = tiles-A waves, 1 = tiles-B waves
    const int w4   = wave & 3;
    const int lane = tid & 63;
    const int quad = lane >> 4;
    const int l16  = lane & 15;
    const int g = blockIdx.x;
    const int xcd = g & 7, slot = g >> 3;
    const int G = (slot >> 4) * 8 + xcd;    // 0..31 = (b,h) group
    const int qtA = slot & 15;              // 0..15
    const int qtB = 31 - qtA;               // 31..16
    const int b = G & 1, h = G >> 1;
    const size_t base = ((size_t)b * 2048) * 1024 + (size_t)h * 64;

    int myqt = grp ? qtB : qtA;
    short8 qf[2];
    {
        const size_t r = base + (size_t)(myqt * 64 + w4 * 16 + l16) * 1024;
        qf[0] = *reinterpret_cast<const short8*>(Q + r + quad * 8);
        qf[1] = *reinterpret_cast<const short8*>(Q + r + 32 + quad * 8);
    }

    float4v o[4];
#pragma unroll
    for (int i = 0; i < 4; i++) o[i] = (float4v){0.f,0.f,0.f,0.f};
    float s = 0.f;

    // V staging coords (512 threads: 8 u16 each per buffer)
    const int srow = tid >> 3;             // 0..63
    const int c0   = (tid & 7) << 3;       // 0,8,...,56
    const int sxw  = srow ^ ((c0 >> 4) << 4);   // swizzled s for d in [c0,c0+8)

    const u16* Vbase = V + base + (size_t)srow * 1024 + c0;
    const u16* kbase = K + base + (size_t)l16 * 1024 + quad * 8;
    int4 vrA = *reinterpret_cast<const int4*>(Vbase);   // tile 0
    int4 vrB;                                           // valid from i=qtA+1

    // bpermute byte-addrs: src lane = ((quad&1)*2 + (j>>1))*16 + l16
    const int bpa0 = (((quad & 1) * 2) * 16 + l16) * 4;
    const int bpa1 = bpa0 + 64;
    const bool hiq = quad >= 2;
    const int qloc = w4 * 16 + l16;        // lane's q-row within its tile

    for (int i = 0; i <= 16; ++i) {
        const int tb = (i <= qtA) ? i : i + 16 - qtA;   // grp-B KV tile

        if (grp == 0 && i == qtA + 1) {    // finalize tile A, switch to B
            float t = s;
            t += __shfl_xor(t, 16); t += __shfl_xor(t, 32);
#pragma unroll
            for (int r = 0; r < 4; r++) {
                const int rl = quad * 4 + r;
                const float inv = 1.0f / __shfl(t, rl);
                const size_t row = base + (size_t)(qtA * 64 + w4 * 16 + rl) * 1024;
#pragma unroll
                for (int dt = 0; dt < 4; dt++)
                    O[row + dt * 16 + l16] = f2b(o[dt][r] * inv);
            }
#pragma unroll
            for (int k = 0; k < 4; k++) o[k] = (float4v){0.f,0.f,0.f,0.f};
            s = 0.f;
            myqt = qtB;
            const size_t r = base + (size_t)(qtB * 64 + w4 * 16 + l16) * 1024;
            qf[0] = *reinterpret_cast<const short8*>(Q + r + quad * 8);
            qf[1] = *reinterpret_cast<const short8*>(Q + r + 32 + quad * 8);
        }

        const int mytile = grp ? tb : i;
        const bool active = (grp == 0) || (tb <= qtB);

        short8 kc[4][2];                   // K frags: issue before barriers
        if (active) {
            const u16* kp = kbase + (size_t)mytile * 65536;
#pragma unroll
            for (int nt = 0; nt < 4; nt++)
#pragma unroll
                for (int ks = 0; ks < 2; ks++)
                    kc[nt][ks] = *reinterpret_cast<const short8*>(kp + (size_t)(nt * 16) * 1024 + ks * 32);
        }

        __syncthreads();                   // all waves done with prev Vt
        {
            const u16* a = reinterpret_cast<const u16*>(&vrA);
#pragma unroll
            for (int e = 0; e < 8; e++) sm.vt[0][(c0 + e) * VSTR + sxw] = a[e];
        }
        if (i > qtA && tb <= qtB) {
            const u16* a = reinterpret_cast<const u16*>(&vrB);
#pragma unroll
            for (int e = 0; e < 8; e++) sm.vt[1][(c0 + e) * VSTR + sxw] = a[e];
        }
        __syncthreads();

        if (i < 16) {                      // prefetch next-iter V tiles
            vrA = *reinterpret_cast<const int4*>(Vbase + (size_t)(i + 1) * 65536);
            if (i + 1 > qtA) {
                const int tbn = i + 17 - qtA;
                if (tbn <= qtB)
                    vrB = *reinterpret_cast<const int4*>(Vbase + (size_t)tbn * 65536);
            }
        }

        if (active) {
            const u16* Vt = sm.vt[(grp && i > qtA) ? 1 : 0];
            // QK (swapped): sacc[nt][r] = S[q=qloc][k=nt*16+quad*4+r]
            float4v sacc[4];
#pragma unroll
            for (int nt = 0; nt < 4; nt++) {
                sacc[nt] = (float4v){0.f, 0.f, 0.f, 0.f};
#pragma unroll
                for (int ks = 0; ks < 2; ks++)
                    sacc[nt] = __builtin_amdgcn_mfma_f32_16x16x32_bf16(kc[nt][ks], qf[ks], sacc[nt], 0, 0, 0);
            }
            // softmax + pack + quad exchange
            const bool diag = (mytile == myqt);
            unsigned int w[4][2];
#pragma unroll
            for (int nt = 0; nt < 4; nt++) {
                float p[4];
#pragma unroll
                for (int r = 0; r < 4; r++) {
                    float sv = sacc[nt][r];                      // log2-domain
                    if (diag && (nt * 16 + quad * 4 + r > qloc)) sv = -1e30f;
                    p[r] = exp2f(sv);
                    s += p[r];
                }
                asm("v_cvt_pk_bf16_f32 %0, %1, %2" : "=v"(w[nt][0]) : "v"(p[0]), "v"(p[1]));
                asm("v_cvt_pk_bf16_f32 %0, %1, %2" : "=v"(w[nt][1]) : "v"(p[2]), "v"(p[3]));
            }
            short8 pa[2];
#pragma unroll
            for (int ks = 0; ks < 2; ks++) {
                unsigned int pw[4];
#pragma unroll
                for (int j = 0; j < 4; j++) {
                    const int addr = (j >> 1) ? bpa1 : bpa0;
                    const int rp = j & 1;
                    int lo_ = __builtin_amdgcn_ds_bpermute(addr, (int)w[2 * ks][rp]);
                    int hi_ = __builtin_amdgcn_ds_bpermute(addr, (int)w[2 * ks + 1][rp]);
                    pw[j] = (unsigned int)(hiq ? hi_ : lo_);
                }
                union { unsigned int u[4]; short8 s8; } t;
                t.u[0] = pw[0]; t.u[1] = pw[1]; t.u[2] = pw[2]; t.u[3] = pw[3];
                pa[ks] = t.s8;
            }
            // PV: vf loaded per-ks (16 VGPR live instead of 32)
#pragma unroll
            for (int ks = 0; ks < 2; ks++) {
                short8 vfk[4];
#pragma unroll
                for (int dt = 0; dt < 4; dt++)
                    vfk[dt] = *reinterpret_cast<const short8*>(&Vt[(dt * 16 + l16) * VSTR + ((ks * 32 + quad * 8) ^ (dt << 4))]);
#pragma unroll
                for (int dt = 0; dt < 4; dt++)
                    o[dt] = __builtin_amdgcn_mfma_f32_16x16x32_bf16(pa[ks], vfk[dt], o[dt], 0, 0, 0);
            }
        }
    }

    // epilogue: merge tile-B partials (grpA holds tiles qtA+1..16 part)
    __syncthreads();
    if (grp == 0) {
#pragma unroll
        for (int dt = 0; dt < 4; dt++)
#pragma unroll
            for (int r = 0; r < 4; r++) sm.m.o[w4][lane][dt * 4 + r] = o[dt][r];
        sm.m.s[w4][lane] = s;
    }
    __syncthreads();
    if (grp == 1) {
        float t = s + sm.m.s[w4][lane];
#pragma unroll
        for (int dt = 0; dt < 4; dt++)
#pragma unroll
            for (int r = 0; r < 4; r++) o[dt][r] += sm.m.o[w4][lane][dt * 4 + r];
        t += __shfl_xor(t, 16); t += __shfl_xor(t, 32);
#pragma unroll
        for (int r = 0; r < 4; r++) {
            const int rl = quad * 4 + r;
            const float inv = 1.0f / __shfl(t, rl);
            const size_t row = base + (size_t)(qtB * 64 + w4 * 16 + rl) * 1024;
#pragma unroll
            for (int dt = 0; dt < 4; dt++)
                O[row + dt * 16 + l16] = f2b(o[dt][r] * inv);
        }
    }
}

// ---------------------------------------------------------------------------
extern "C" void kernel_launch(void* const* d_in, const int* in_sizes, int n_in,
                              void* d_out, int out_size, void* d_ws, size_t ws_size,
                              hipStream_t stream) {
    (void)in_sizes; (void)n_in; (void)out_size; (void)ws_size;
    const float* x  = (const float*)d_in[0];
    const float* wq = (const float*)d_in[1];
    const float* wk = (const float*)d_in[2];
    const float* wv = (const float*)d_in[3];
    const float* wo = (const float*)d_in[4];

    const size_t MN = (size_t)4096 * 1024;

    // d_out (16MB): xb (8MB) + wcat (6MB) + rope table (512KB in free tail);
    // all consumed before the final fp32 GEMM overwrites d_out.
    u16* xb   = (u16*)d_out;
    u16* wcat = xb + MN;                    // [3072][1024] = wq|wk|wv rows
    float2* tab = (float2*)(wcat + (size_t)3072 * 1024);
    u16* qbuf = (u16*)d_ws;                 // also attention output
    u16* kbuf = qbuf + MN;
    u16* vbuf = kbuf + MN;
    u16* wob  = vbuf + MN;                  // ws total: 26MB

    cvt_all<<<4096, 256, 0, stream>>>((const float4*)x, (const float4*)wq,
                                      (const float4*)wk, (const float4*)wv,
                                      (const float4*)wo, xb, wcat, wob);
    rope_tab<<<256, 256, 0, stream>>>(tab);
    gemm_tile<4, 1, 24><<<768, 256, 0, stream>>>(xb, wcat, qbuf, kbuf, vbuf, nullptr, tab);
    attn_kernel<<<512, 512, 0, stream>>>(qbuf, kbuf, vbuf, qbuf);
    gemm_tile<2, 0, 16><<<512, 256, 0, stream>>>(qbuf, wob, nullptr, nullptr, nullptr, (float*)d_out, nullptr);
}